// Round 2
// baseline (2759456.445 us; speedup 1.0000x reference)
//
#include <hip/hip_runtime.h>

#define TSTEPS 784
#define BATCH  256
#define HDIM   512
#define NCLS   10
#define NGRP   16
#define WGPG   8

typedef __bf16 bf16x8 __attribute__((ext_vector_type(8)));
typedef float  f32x4  __attribute__((ext_vector_type(4)));
typedef unsigned uint4v __attribute__((ext_vector_type(4)));
typedef unsigned long long u64;
typedef unsigned short u16;

static __device__ __forceinline__ u16 f2bf(float f) {
  unsigned u = __builtin_bit_cast(unsigned, f);
  u += 0x7fffu + ((u >> 16) & 1u);
  return (u16)(u >> 16);
}
static __device__ __forceinline__ float bf2f(unsigned s) {
  unsigned u = s << 16;
  return __builtin_bit_cast(float, u);
}

// ---------------- xp[t][b] = inputs[b][perm[t]] ----------------
__global__ __launch_bounds__(256) void gather_xp(const float* __restrict__ in,
                                                 const int* __restrict__ perm,
                                                 float* __restrict__ xp) {
  int t = blockIdx.x;
  int b = threadIdx.x;
  int p = perm[t];
  p = (p < 0) ? 0 : (p >= TSTEPS ? TSTEPS - 1 : p);
  xp[t * BATCH + b] = in[b * TSTEPS + p];
}

// ---------------- X = (triu(W,1) - triu(W,1)^T) / 32 ----------------
__global__ __launch_bounds__(256) void build_X(const float* __restrict__ W,
                                               float* __restrict__ X) {
  int idx = blockIdx.x * 256 + threadIdx.x;
  int i = idx >> 9, j = idx & 511;
  float v = 0.f;
  if (j > i) v = W[i * HDIM + j];
  else if (i > j) v = -W[j * HDIM + i];
  X[idx] = v * 0.03125f;
}

// ---------------- P = coef*X + I ----------------
__global__ __launch_bounds__(256) void axpyI(float* __restrict__ P,
                                             const float* __restrict__ X, float coef) {
  int idx = blockIdx.x * 256 + threadIdx.x;
  int i = idx >> 9, j = idx & 511;
  P[idx] = coef * X[idx] + ((i == j) ? 1.f : 0.f);
}

// ---------------- C = alpha*A*B (+I), 512^3 fp32, 64x64 tile ----------------
// fp32 vector GEMM [R2-R8 proven]. The expm chain NEEDS fp32-class accuracy:
// split-bf16 here gave delta(Borth) ~1e-2 after 5 squarings -> absmax 12 (R9).
__global__ __launch_bounds__(256) void gemm512(float* __restrict__ C,
                                               const float* __restrict__ A,
                                               const float* __restrict__ B,
                                               float alpha, int addI) {
  __shared__ float As[16][68];
  __shared__ float Bs[16][68];
  const int tx = threadIdx.x, ty = threadIdx.y;
  const int tid = ty * 16 + tx;
  const int ib = blockIdx.y, jb = blockIdx.x;
  const int ra = tid >> 2, ca = (tid & 3) << 2;
  const int rb = tid >> 4, cb = (tid & 15) << 2;
  float acc[4][4] = {};
  for (int kt = 0; kt < HDIM / 16; ++kt) {
    f32x4 av = *(const f32x4*)(A + (ib * 64 + ra) * HDIM + kt * 16 + ca);
    f32x4 bv = *(const f32x4*)(B + (kt * 16 + rb) * HDIM + jb * 64 + cb);
    __syncthreads();
    As[ca + 0][ra] = av[0];
    As[ca + 1][ra] = av[1];
    As[ca + 2][ra] = av[2];
    As[ca + 3][ra] = av[3];
    *(f32x4*)&Bs[rb][cb] = bv;
    __syncthreads();
#pragma unroll
    for (int kk = 0; kk < 16; ++kk) {
      f32x4 a4 = *(const f32x4*)&As[kk][ty << 2];
      f32x4 b4 = *(const f32x4*)&Bs[kk][tx << 2];
#pragma unroll
      for (int u = 0; u < 4; ++u)
#pragma unroll
        for (int v = 0; v < 4; ++v) acc[u][v] = fmaf(a4[u], b4[v], acc[u][v]);
    }
  }
#pragma unroll
  for (int u = 0; u < 4; ++u)
#pragma unroll
    for (int v = 0; v < 4; ++v) {
      int r = ib * 64 + (ty << 2) + u, c = jb * 64 + (tx << 2) + v;
      float val = alpha * acc[u][v];
      if (addI && r == c) val += 1.f;
      C[r * HDIM + c] = val;
    }
}

// ---------------- persistent RNN scan [R11: hardened R10 sc0 fast path] ----
// R10 theory: group gb's 8 WGs (wg==gb mod 8) land on one XCD; runtime
// HW_REG_XCC_ID handshake verifies; if all 8 agree, group communication
// (h planes + flags) uses sc0 (SE-scope: L1-bypass, XCD-L2 coherence point)
// instead of agent scope (LLC round trips + HBM write-through). R1 bench
// died signatureless -- possibly a hang via the 0.18s/step spin valve if
// sc0 visibility were wrong (784 steps -> timeout). R11: valve cut to 1<<15
// (total worst-case spin ~1s, run COMPLETES and tells us which branch
// failed); handshake valves bounded at 1<<20 (fail-safe to slow path).
template <bool SE>
static __device__ __forceinline__ void rnn_loop(
    const float* __restrict__ xp, const float* __restrict__ Borth,
    const float* __restrict__ W_in, const float* __restrict__ b_mod,
    const float* __restrict__ W_lin, const float* __restrict__ b_lin,
    u16* g0h, u16* g0l, u16* g1h, u16* g1l, unsigned* myflag, unsigned* gflags,
    float* __restrict__ out, unsigned* tileHi, unsigned* tileLo, int tid,
    int gb, int cg) {
  const int wave = tid >> 6;
  const int lane = tid & 63;
  const int quad = lane >> 4;
  const int l16 = lane & 15;
  const int colg = (cg << 6) + (wave << 4) + l16;

  // B fragments, register/AGPR-resident (round-hi split, R3-proven numerics)
  bf16x8 Bfh[16], Bfl[16];
#pragma unroll
  for (int ki = 0; ki < 16; ++ki) {
#pragma unroll
    for (int j = 0; j < 8; ++j) {
      int k = (ki << 5) + (quad << 3) + j;
      float v = Borth[k * HDIM + colg];
      u16 hb = f2bf(v);
      u16 lb = f2bf(v - bf2f(hb));
      Bfh[ki][j] = __builtin_bit_cast(__bf16, hb);
      Bfl[ki][j] = __builtin_bit_cast(__bf16, lb);
    }
  }
  const float win = W_in[colg];
  const float bm = b_mod[colg];
  const unsigned swz = (unsigned)((l16 & 7) << 2);

  for (int t = 0; t < TSTEPS; ++t) {
    const u64* __restrict__ cH = (const u64*)((t & 1) ? g1h : g0h);
    const u64* __restrict__ cL = (const u64*)((t & 1) ? g1l : g0l);
    u16* __restrict__ nH = (t & 1) ? g0h : g1h;
    u16* __restrict__ nL = (t & 1) ? g0l : g1l;

    // ---- cooperative stage: 2048 u64 per plane; 16 loads in flight ----
    u64 qh[8], ql[8];
    if (SE) {
#pragma unroll
      for (int i = 0; i < 8; ++i)
        asm volatile("global_load_dwordx2 %0, %1, off sc0"
                     : "=&v"(qh[i]) : "v"(cH + tid + (i << 8)));
#pragma unroll
      for (int i = 0; i < 8; ++i)
        asm volatile("global_load_dwordx2 %0, %1, off sc0"
                     : "=&v"(ql[i]) : "v"(cL + tid + (i << 8)));
      asm volatile("s_waitcnt vmcnt(0)" ::: "memory");
      __builtin_amdgcn_sched_barrier(0);  // rule #18: pin consumers below wait
    } else {
#pragma unroll
      for (int i = 0; i < 8; ++i) {
        qh[i] = __hip_atomic_load(cH + tid + (i << 8), __ATOMIC_RELAXED,
                                  __HIP_MEMORY_SCOPE_AGENT);
        ql[i] = __hip_atomic_load(cL + tid + (i << 8), __ATOMIC_RELAXED,
                                  __HIP_MEMORY_SCOPE_AGENT);
      }
    }
#pragma unroll
    for (int i = 0; i < 8; ++i) {
      int f = tid + (i << 8);                  // u64 index in 2048-u64 plane
      int r = f >> 7;                          // row 0..15
      unsigned du = (unsigned)(f & 127) << 1;  // dword col (even)
      unsigned phys = ((unsigned)r << 8) | (du ^ ((r & 7) << 2));
      *(u64*)(tileHi + phys) = qh[i];
      *(u64*)(tileLo + phys) = ql[i];
    }
    __syncthreads();

    // ---- fragment reads (swizzled, NO perms) + split-bf16 MFMA ----
    f32x4 a_hh = {0.f, 0.f, 0.f, 0.f};
    f32x4 a_lh = {0.f, 0.f, 0.f, 0.f};
    f32x4 a_hl = {0.f, 0.f, 0.f, 0.f};
#pragma unroll
    for (int ki = 0; ki < 16; ++ki) {
      unsigned dcol0 = (unsigned)((ki << 4) + (quad << 2));
      unsigned off = ((unsigned)l16 << 8) + (dcol0 ^ swz);
      bf16x8 ah = __builtin_bit_cast(bf16x8, *(const uint4v*)(tileHi + off));
      bf16x8 al = __builtin_bit_cast(bf16x8, *(const uint4v*)(tileLo + off));
      a_hh = __builtin_amdgcn_mfma_f32_16x16x32_bf16(ah, Bfh[ki], a_hh, 0, 0, 0);
      a_lh = __builtin_amdgcn_mfma_f32_16x16x32_bf16(al, Bfh[ki], a_lh, 0, 0, 0);
      a_hl = __builtin_amdgcn_mfma_f32_16x16x32_bf16(ah, Bfl[ki], a_hl, 0, 0, 0);
    }

    // C/D layout: row = quad*4 + r, col = l16  [R3-proven]
    const f32x4 xps = *(const f32x4*)(xp + t * BATCH + (gb << 4) + (quad << 2));
#pragma unroll
    for (int r = 0; r < 4; ++r) {
      float pre = a_hh[r] + a_lh[r] + a_hl[r] + xps[r] * win;
      float mm = fmaxf(fabsf(pre) + bm, 0.f);
      float hv = (pre > 0.f) ? mm : ((pre < 0.f) ? -mm : 0.f);
      int idx = (((quad << 2) + r) << 9) + colg;
      u16 hbv = f2bf(hv);
      u16 lbv = f2bf(hv - bf2f(hbv));
      if (SE) {
        unsigned h32 = hbv, l32 = lbv;
        asm volatile("global_store_short %0, %1, off sc0" ::"v"(nH + idx),
                     "v"(h32));
        asm volatile("global_store_short %0, %1, off sc0" ::"v"(nL + idx),
                     "v"(l32));
      } else {
        __hip_atomic_store(nH + idx, hbv, __ATOMIC_RELAXED,
                           __HIP_MEMORY_SCOPE_AGENT);
        __hip_atomic_store(nL + idx, lbv, __ATOMIC_RELAXED,
                           __HIP_MEMORY_SCOPE_AGENT);
      }
    }

    // ---- flag barrier (8 WGs per group) [R6-proven; sc0 ack at L2 in SE] --
    asm volatile("s_waitcnt vmcnt(0)" ::: "memory");  // planes at coherence pt
    __syncthreads();
    const unsigned target = (unsigned)(t + 1);
    if (tid == 0) {
      if (SE)
        asm volatile("global_store_dword %0, %1, off sc0" ::"v"(myflag),
                     "v"(target));
      else
        __hip_atomic_store(myflag, target, __ATOMIC_RELAXED,
                           __HIP_MEMORY_SCOPE_AGENT);
    }
    int spin = 0;
    for (;;) {
      unsigned fl;
      if (SE)
        asm volatile("global_load_dword %0, %1, off sc0\n\ts_waitcnt vmcnt(0)"
                     : "=&v"(fl) : "v"(gflags + (lane & 7) * 32) : "memory");
      else
        fl = __hip_atomic_load(gflags + (lane & 7) * 32, __ATOMIC_RELAXED,
                               __HIP_MEMORY_SCOPE_AGENT);
      if (__ballot(fl >= target) == ~0ull) break;
      __builtin_amdgcn_s_sleep(1);
      if (++spin > (1 << 15)) break;  // R11: small valve -> run completes,
                                      // never times out the harness
    }
    __builtin_amdgcn_sched_barrier(0);  // no hoisting of next stage above spin
  }

  // ---- head: final h in buffer 0 (t=783 odd -> writes g0). Stage to LDS
  // with path-matched scope (fast path data may be dirty only in XCD L2).
  if (cg == 0) {
    const u64* fH = (const u64*)g0h;
    const u64* fL = (const u64*)g0l;
    u64 qh[8], ql[8];
    if (SE) {
#pragma unroll
      for (int i = 0; i < 8; ++i)
        asm volatile("global_load_dwordx2 %0, %1, off sc0"
                     : "=&v"(qh[i]) : "v"(fH + tid + (i << 8)));
#pragma unroll
      for (int i = 0; i < 8; ++i)
        asm volatile("global_load_dwordx2 %0, %1, off sc0"
                     : "=&v"(ql[i]) : "v"(fL + tid + (i << 8)));
      asm volatile("s_waitcnt vmcnt(0)" ::: "memory");
      __builtin_amdgcn_sched_barrier(0);
    } else {
#pragma unroll
      for (int i = 0; i < 8; ++i) {
        qh[i] = __hip_atomic_load(fH + tid + (i << 8), __ATOMIC_RELAXED,
                                  __HIP_MEMORY_SCOPE_AGENT);
        ql[i] = __hip_atomic_load(fL + tid + (i << 8), __ATOMIC_RELAXED,
                                  __HIP_MEMORY_SCOPE_AGENT);
      }
    }
#pragma unroll
    for (int i = 0; i < 8; ++i) {
      int f = tid + (i << 8);
      int r = f >> 7;
      unsigned du = (unsigned)(f & 127) << 1;
      unsigned phys = ((unsigned)r << 8) | (du ^ ((r & 7) << 2));
      *(u64*)(tileHi + phys) = qh[i];
      *(u64*)(tileLo + phys) = ql[i];
    }
    __syncthreads();
    int row = tid >> 4;
    int cls = tid & 15;
    if (cls < NCLS) {
      float s = b_lin[cls];
      const float* wl = W_lin + cls * HDIM;
      for (int k = 0; k < HDIM; ++k) {
        unsigned phys = ((unsigned)row << 8) |
                        (((unsigned)k >> 1) ^ (((unsigned)row & 7) << 2));
        unsigned sh = ((unsigned)k & 1) << 4;
        float hv = bf2f((tileHi[phys] >> sh) & 0xFFFFu) +
                   bf2f((tileLo[phys] >> sh) & 0xFFFFu);
        s = fmaf(hv, wl[k], s);
      }
      out[((gb << 4) + row) * NCLS + cls] = s;
    }
  }
}

__global__ __launch_bounds__(256, 1) void rnn_main(
    const float* __restrict__ xp, const float* __restrict__ Borth,
    const float* __restrict__ W_in, const float* __restrict__ b_mod,
    const float* __restrict__ W_lin, const float* __restrict__ b_lin,
    u16* __restrict__ h0hi, u16* __restrict__ h0lo, u16* __restrict__ h1hi,
    u16* __restrict__ h1lo, unsigned* __restrict__ flags, float* __restrict__ out) {
  __shared__ unsigned tileHi[4096], tileLo[4096];  // 16 KB + 16 KB
  __shared__ unsigned fast_sh;

  const int wg = blockIdx.x;
  const int gb = wg & 15;
  const int cg = wg >> 4;
  const int tid = threadIdx.x;

  // ---- handshake: is this group entirely on one XCD? (device scope; two
  // rounds so all 8 members provably agree on the same path; any timeout
  // fails safe to the slow path) ----
  if (tid == 0) {
    unsigned xcd;
    asm volatile("s_getreg_b32 %0, hwreg(HW_REG_XCC_ID)" : "=s"(xcd));
    unsigned* xslot = flags + 4096;         // [4096..4223], memset 0
    unsigned* aslot = flags + 4096 + 256;   // [4352..4479], memset 0
    __hip_atomic_store(xslot + wg, xcd + 1u, __ATOMIC_RELAXED,
                       __HIP_MEMORY_SCOPE_AGENT);
    unsigned fast = 1u;
    for (int c = 0; c < WGPG; ++c) {
      unsigned v = 0;
      int sp = 0;
      do {
        v = __hip_atomic_load(xslot + c * NGRP + gb, __ATOMIC_RELAXED,
                              __HIP_MEMORY_SCOPE_AGENT);
        if (!v) __builtin_amdgcn_s_sleep(1);
      } while (!v && ++sp < (1 << 20));
      if (v != xcd + 1u) fast = 0u;
    }
    __hip_atomic_store(aslot + wg, fast + 1u, __ATOMIC_RELAXED,
                       __HIP_MEMORY_SCOPE_AGENT);
    unsigned all = 1u;
    for (int c = 0; c < WGPG; ++c) {
      unsigned v = 0;
      int sp = 0;
      do {
        v = __hip_atomic_load(aslot + c * NGRP + gb, __ATOMIC_RELAXED,
                              __HIP_MEMORY_SCOPE_AGENT);
        if (!v) __builtin_amdgcn_s_sleep(1);
      } while (!v && ++sp < (1 << 20));
      if (v != 2u) all = 0u;
    }
    fast_sh = all;
  }
  __syncthreads();
  const bool fast = (fast_sh != 0u);

  u16* const g0h = h0hi + (gb << 13);  // 8192 u16 per group-plane
  u16* const g0l = h0lo + (gb << 13);
  u16* const g1h = h1hi + (gb << 13);
  u16* const g1l = h1lo + (gb << 13);
  unsigned* const myflag = flags + ((gb << 3) + cg) * 32;
  unsigned* const gflags = flags + (gb << 3) * 32;

  if (fast)
    rnn_loop<true>(xp, Borth, W_in, b_mod, W_lin, b_lin, g0h, g0l, g1h, g1l,
                   myflag, gflags, out, tileHi, tileLo, tid, gb, cg);
  else
    rnn_loop<false>(xp, Borth, W_in, b_mod, W_lin, b_lin, g0h, g0l, g1h, g1l,
                    myflag, gflags, out, tileHi, tileLo, tid, gb, cg);
}

extern "C" void kernel_launch(void* const* d_in, const int* in_sizes, int n_in,
                              void* d_out, int out_size, void* d_ws, size_t ws_size,
                              hipStream_t stream) {
  const float* inputs = (const float*)d_in[0];  // 256x784
  const int* perm = (const int*)d_in[1];        // 784 (int64 -> int32 by harness)
  const float* W_skew = (const float*)d_in[2];  // 512x512
  const float* W_in = (const float*)d_in[3];    // 512
  const float* b_mod = (const float*)d_in[4];   // 512
  const float* W_lin = (const float*)d_in[5];   // 10x512
  const float* b_lin = (const float*)d_in[6];   // 10
  float* out = (float*)d_out;

  char* ws = (char*)d_ws;
  unsigned* flags = (unsigned*)ws;            // 32 KB (step flags + handshake)
  u16* h0hi = (u16*)(ws + 32768);             // 4 planes x 256 KB = 1 MB
  u16* h0lo = h0hi + BATCH * HDIM;
  u16* h1hi = h0lo + BATCH * HDIM;
  u16* h1lo = h1hi + BATCH * HDIM;
  float* xp = (float*)(h1lo + BATCH * HDIM);  // 0.77 MB
  float* X = xp + TSTEPS * BATCH;             // 1 MB
  float* P = X + HDIM * HDIM;                 // 1 MB
  float* Q = P + HDIM * HDIM;                 // 1 MB  (total ~4.9 MB)

  hipMemsetAsync(flags, 0, 32768, stream);
  hipMemsetAsync(h0hi, 0, (size_t)BATCH * HDIM * 2 * sizeof(u16), stream);  // h0 hi+lo

  gather_xp<<<TSTEPS, 256, 0, stream>>>(inputs, perm, xp);
  build_X<<<(HDIM * HDIM) / 256, 256, 0, stream>>>(W_skew, X);

  // expm(A) = (T6(A/32))^(2^5), Horner -- fp32 gemm512 [R2-R8 proven numerics]
  axpyI<<<(HDIM * HDIM) / 256, 256, 0, stream>>>(P, X, 1.f / 6.f);
  float* a = P;
  float* b = Q;
  for (int k = 5; k >= 1; --k) {
    gemm512<<<dim3(8, 8), dim3(16, 16), 0, stream>>>(b, X, a, 1.f / (float)k, 1);
    float* tmp = a; a = b; b = tmp;
  }
  for (int i = 0; i < 5; ++i) {
    gemm512<<<dim3(8, 8), dim3(16, 16), 0, stream>>>(b, a, a, 1.f, 0);
    float* tmp = a; a = b; b = tmp;
  }
  // a == P (10 swaps -> back to P)

  rnn_main<<<NGRP * WGPG, 256, 0, stream>>>(xp, a, W_in, b_mod, W_lin, b_lin,
                                            h0hi, h0lo, h1hi, h1lo, flags, out);
  (void)in_sizes; (void)n_in; (void)out_size; (void)ws_size;
}

// Round 3
// 4452.530 us; speedup vs baseline: 619.7502x; 619.7502x over previous
//
#include <hip/hip_runtime.h>

#define TSTEPS 784
#define BATCH  256
#define HDIM   512
#define NCLS   10
#define NGRP   16
#define WGPG   8
#define NPAIR  8

typedef __bf16 bf16x8 __attribute__((ext_vector_type(8)));
typedef float  f32x4  __attribute__((ext_vector_type(4)));
typedef unsigned uint4v __attribute__((ext_vector_type(4)));
typedef unsigned long long u64;
typedef unsigned short u16;

static __device__ __forceinline__ u16 f2bf(float f) {
  unsigned u = __builtin_bit_cast(unsigned, f);
  u += 0x7fffu + ((u >> 16) & 1u);
  return (u16)(u >> 16);
}
static __device__ __forceinline__ float bf2f(unsigned s) {
  unsigned u = s << 16;
  return __builtin_bit_cast(float, u);
}

// ---------------- xp[t][b] = inputs[b][perm[t]] ----------------
__global__ __launch_bounds__(256) void gather_xp(const float* __restrict__ in,
                                                 const int* __restrict__ perm,
                                                 float* __restrict__ xp) {
  int t = blockIdx.x;
  int b = threadIdx.x;
  int p = perm[t];
  p = (p < 0) ? 0 : (p >= TSTEPS ? TSTEPS - 1 : p);
  xp[t * BATCH + b] = in[b * TSTEPS + p];
}

// ---------------- X = (triu(W,1) - triu(W,1)^T) / 32 ----------------
__global__ __launch_bounds__(256) void build_X(const float* __restrict__ W,
                                               float* __restrict__ X) {
  int idx = blockIdx.x * 256 + threadIdx.x;
  int i = idx >> 9, j = idx & 511;
  float v = 0.f;
  if (j > i) v = W[i * HDIM + j];
  else if (i > j) v = -W[j * HDIM + i];
  X[idx] = v * 0.03125f;
}

// ---------------- P = coef*X + I ----------------
__global__ __launch_bounds__(256) void axpyI(float* __restrict__ P,
                                             const float* __restrict__ X, float coef) {
  int idx = blockIdx.x * 256 + threadIdx.x;
  int i = idx >> 9, j = idx & 511;
  P[idx] = coef * X[idx] + ((i == j) ? 1.f : 0.f);
}

// ---------------- C = alpha*A*B (+I), 512^3 fp32, 64x64 tile ----------------
// fp32 vector GEMM [R2-R8 proven]. The expm chain NEEDS fp32-class accuracy:
// split-bf16 here gave delta(Borth) ~1e-2 after 5 squarings -> absmax 12 (R9).
__global__ __launch_bounds__(256) void gemm512(float* __restrict__ C,
                                               const float* __restrict__ A,
                                               const float* __restrict__ B,
                                               float alpha, int addI) {
  __shared__ float As[16][68];
  __shared__ float Bs[16][68];
  const int tx = threadIdx.x, ty = threadIdx.y;
  const int tid = ty * 16 + tx;
  const int ib = blockIdx.y, jb = blockIdx.x;
  const int ra = tid >> 2, ca = (tid & 3) << 2;
  const int rb = tid >> 4, cb = (tid & 15) << 2;
  float acc[4][4] = {};
  for (int kt = 0; kt < HDIM / 16; ++kt) {
    f32x4 av = *(const f32x4*)(A + (ib * 64 + ra) * HDIM + kt * 16 + ca);
    f32x4 bv = *(const f32x4*)(B + (kt * 16 + rb) * HDIM + jb * 64 + cb);
    __syncthreads();
    As[ca + 0][ra] = av[0];
    As[ca + 1][ra] = av[1];
    As[ca + 2][ra] = av[2];
    As[ca + 3][ra] = av[3];
    *(f32x4*)&Bs[rb][cb] = bv;
    __syncthreads();
#pragma unroll
    for (int kk = 0; kk < 16; ++kk) {
      f32x4 a4 = *(const f32x4*)&As[kk][ty << 2];
      f32x4 b4 = *(const f32x4*)&Bs[kk][tx << 2];
#pragma unroll
      for (int u = 0; u < 4; ++u)
#pragma unroll
        for (int v = 0; v < 4; ++v) acc[u][v] = fmaf(a4[u], b4[v], acc[u][v]);
    }
  }
#pragma unroll
  for (int u = 0; u < 4; ++u)
#pragma unroll
    for (int v = 0; v < 4; ++v) {
      int r = ib * 64 + (ty << 2) + u, c = jb * 64 + (tx << 2) + v;
      float val = alpha * acc[u][v];
      if (addI && r == c) val += 1.f;
      C[r * HDIM + c] = val;
    }
}

// ---------------- persistent RNN scan [R12: two-chain multiplex] ------------
// R11 post-mortem: sc0 (SE scope) flags never become visible across CUs on
// gfx950 (run completed only via the spin valve, 3.5ms/step). Scope games
// dead; agent scope only. R12 lever: the 16 batch-group chains are
// INDEPENDENT. One WG now serves chains A=2p, B=2p+1: both chains' stage
// loads issued back-to-back (latency overlaps), compute/drain A while B's
// loads fly, ONE fused spin over all 16 flags. 64 WGs x 64KB LDS.
// Also: operand-swapped MFMA -- mfma(Bf, h_frag) computes pre^T so each
// thread owns 4 CONSECUTIVE h-cols at one batch row -> epilogue is one
// packed u64 store per plane (vs 8 scattered global_store_short). Fragment
// layouts A(i=l&15,k=(l>>4)*8+j) / B(col=l&15,k=(l>>4)*8+j) / D(row=q*4+r,
// col=l16) all proven by the R6-R11 kernel; arithmetic bitwise identical.
__global__ __launch_bounds__(256, 1) void rnn_main(
    const float* __restrict__ xp, const float* __restrict__ Borth,
    const float* __restrict__ W_in, const float* __restrict__ b_mod,
    const float* __restrict__ W_lin, const float* __restrict__ b_lin,
    u16* __restrict__ h0hi, u16* __restrict__ h0lo, u16* __restrict__ h1hi,
    u16* __restrict__ h1lo, unsigned* __restrict__ flags, float* __restrict__ out) {
  __shared__ unsigned tHiA[4096], tLoA[4096];  // 16 KB x 4 = 64 KB
  __shared__ unsigned tHiB[4096], tLoB[4096];

  const int wg = blockIdx.x;
  const int pr = wg & (NPAIR - 1);
  const int cg = wg >> 3;  // 0..7 column-slice
  const int gbA = pr << 1, gbB = (pr << 1) | 1;
  const int tid = threadIdx.x;
  const int wave = tid >> 6;
  const int lane = tid & 63;
  const int quad = lane >> 4;
  const int l16 = lane & 15;
  const int colg = (cg << 6) + (wave << 4) + l16;           // Bf column
  const int hbase = (cg << 6) + (wave << 4) + (quad << 2);  // epilogue h-col base

  // Borth fragments (round-hi split, R3-proven numerics; shared by chains)
  bf16x8 Bfh[16], Bfl[16];
#pragma unroll
  for (int ki = 0; ki < 16; ++ki) {
#pragma unroll
    for (int j = 0; j < 8; ++j) {
      int k = (ki << 5) + (quad << 3) + j;
      float v = Borth[k * HDIM + colg];
      u16 hb = f2bf(v);
      u16 lb = f2bf(v - bf2f(hb));
      Bfh[ki][j] = __builtin_bit_cast(__bf16, hb);
      Bfl[ki][j] = __builtin_bit_cast(__bf16, lb);
    }
  }
  const f32x4 win4 = *(const f32x4*)(W_in + hbase);
  const f32x4 bm4 = *(const f32x4*)(b_mod + hbase);

  u16* const g0hA = h0hi + (gbA << 13);
  u16* const g0lA = h0lo + (gbA << 13);
  u16* const g1hA = h1hi + (gbA << 13);
  u16* const g1lA = h1lo + (gbA << 13);
  u16* const g0hB = h0hi + (gbB << 13);
  u16* const g0lB = h0lo + (gbB << 13);
  u16* const g1hB = h1hi + (gbB << 13);
  u16* const g1lB = h1lo + (gbB << 13);
  unsigned* const myflagA = flags + (((gbA << 3) + cg) << 5);
  unsigned* const myflagB = flags + (((gbB << 3) + cg) << 5);
  unsigned* const poll = flags + ((gbA << 3) << 5);  // 16 consecutive slots
  const unsigned swz = (unsigned)((l16 & 7) << 2);

  for (int t = 0; t < TSTEPS; ++t) {
    const u64* __restrict__ cHA = (const u64*)((t & 1) ? g1hA : g0hA);
    const u64* __restrict__ cLA = (const u64*)((t & 1) ? g1lA : g0lA);
    u16* __restrict__ nHA = (t & 1) ? g0hA : g1hA;
    u16* __restrict__ nLA = (t & 1) ? g0lA : g1lA;
    const u64* __restrict__ cHB = (const u64*)((t & 1) ? g1hB : g0hB);
    const u64* __restrict__ cLB = (const u64*)((t & 1) ? g1lB : g0lB);
    u16* __restrict__ nHB = (t & 1) ? g0hB : g1hB;
    u16* __restrict__ nLB = (t & 1) ? g0lB : g1lB;

    // ---- issue BOTH chains' cooperative stage loads (latencies overlap) ----
    u64 qhA[8], qlA[8], qhB[8], qlB[8];
#pragma unroll
    for (int i = 0; i < 8; ++i) {
      qhA[i] = __hip_atomic_load(cHA + tid + (i << 8), __ATOMIC_RELAXED,
                                 __HIP_MEMORY_SCOPE_AGENT);
      qlA[i] = __hip_atomic_load(cLA + tid + (i << 8), __ATOMIC_RELAXED,
                                 __HIP_MEMORY_SCOPE_AGENT);
    }
#pragma unroll
    for (int i = 0; i < 8; ++i) {
      qhB[i] = __hip_atomic_load(cHB + tid + (i << 8), __ATOMIC_RELAXED,
                                 __HIP_MEMORY_SCOPE_AGENT);
      qlB[i] = __hip_atomic_load(cLB + tid + (i << 8), __ATOMIC_RELAXED,
                                 __HIP_MEMORY_SCOPE_AGENT);
    }

    // ---- chain A: LDS stage, MFMA, epilogue, drain, flag ----
#pragma unroll
    for (int i = 0; i < 8; ++i) {
      int f = tid + (i << 8);                  // u64 index in 2048-u64 plane
      int r = f >> 7;                          // row 0..15
      unsigned du = (unsigned)(f & 127) << 1;  // dword col (even)
      unsigned phys = ((unsigned)r << 8) | (du ^ ((r & 7) << 2));
      *(u64*)(tHiA + phys) = qhA[i];
      *(u64*)(tLoA + phys) = qlA[i];
    }
    __syncthreads();

    f32x4 hhA = {0.f, 0.f, 0.f, 0.f};
    f32x4 lhA = {0.f, 0.f, 0.f, 0.f};
    f32x4 hlA = {0.f, 0.f, 0.f, 0.f};
#pragma unroll
    for (int ki = 0; ki < 16; ++ki) {
      unsigned dcol0 = (unsigned)((ki << 4) + (quad << 2));
      unsigned off = ((unsigned)l16 << 8) + (dcol0 ^ swz);
      bf16x8 ah = __builtin_bit_cast(bf16x8, *(const uint4v*)(tHiA + off));
      bf16x8 al = __builtin_bit_cast(bf16x8, *(const uint4v*)(tLoA + off));
      hhA = __builtin_amdgcn_mfma_f32_16x16x32_bf16(Bfh[ki], ah, hhA, 0, 0, 0);
      lhA = __builtin_amdgcn_mfma_f32_16x16x32_bf16(Bfh[ki], al, lhA, 0, 0, 0);
      hlA = __builtin_amdgcn_mfma_f32_16x16x32_bf16(Bfl[ki], ah, hlA, 0, 0, 0);
    }
    {
      // D = pre^T: thread owns batchrow=l16, h-cols hbase+0..3
      float xs = xp[t * BATCH + (gbA << 4) + l16];
      u64 hw = 0, lw = 0;
#pragma unroll
      for (int r = 0; r < 4; ++r) {
        float pre = hhA[r] + lhA[r] + hlA[r] + xs * win4[r];
        float mm = fmaxf(fabsf(pre) + bm4[r], 0.f);
        float hv = (pre > 0.f) ? mm : ((pre < 0.f) ? -mm : 0.f);
        u16 hbv = f2bf(hv);
        u16 lbv = f2bf(hv - bf2f(hbv));
        hw |= ((u64)hbv) << (16 * r);
        lw |= ((u64)lbv) << (16 * r);
      }
      int idx = (l16 << 9) + hbase;  // u16 index; byte-aligned to 8
      __hip_atomic_store((u64*)(nHA + idx), hw, __ATOMIC_RELAXED,
                         __HIP_MEMORY_SCOPE_AGENT);
      __hip_atomic_store((u64*)(nLA + idx), lw, __ATOMIC_RELAXED,
                         __HIP_MEMORY_SCOPE_AGENT);
    }
    asm volatile("s_waitcnt vmcnt(0)" ::: "memory");
    __syncthreads();
    if (tid == 0)
      __hip_atomic_store(myflagA, (unsigned)(t + 1), __ATOMIC_RELAXED,
                         __HIP_MEMORY_SCOPE_AGENT);

    // ---- chain B: LDS stage, MFMA, epilogue, drain, flag ----
#pragma unroll
    for (int i = 0; i < 8; ++i) {
      int f = tid + (i << 8);
      int r = f >> 7;
      unsigned du = (unsigned)(f & 127) << 1;
      unsigned phys = ((unsigned)r << 8) | (du ^ ((r & 7) << 2));
      *(u64*)(tHiB + phys) = qhB[i];
      *(u64*)(tLoB + phys) = qlB[i];
    }
    __syncthreads();

    f32x4 hhB = {0.f, 0.f, 0.f, 0.f};
    f32x4 lhB = {0.f, 0.f, 0.f, 0.f};
    f32x4 hlB = {0.f, 0.f, 0.f, 0.f};
#pragma unroll
    for (int ki = 0; ki < 16; ++ki) {
      unsigned dcol0 = (unsigned)((ki << 4) + (quad << 2));
      unsigned off = ((unsigned)l16 << 8) + (dcol0 ^ swz);
      bf16x8 ah = __builtin_bit_cast(bf16x8, *(const uint4v*)(tHiB + off));
      bf16x8 al = __builtin_bit_cast(bf16x8, *(const uint4v*)(tLoB + off));
      hhB = __builtin_amdgcn_mfma_f32_16x16x32_bf16(Bfh[ki], ah, hhB, 0, 0, 0);
      lhB = __builtin_amdgcn_mfma_f32_16x16x32_bf16(Bfh[ki], al, lhB, 0, 0, 0);
      hlB = __builtin_amdgcn_mfma_f32_16x16x32_bf16(Bfl[ki], ah, hlB, 0, 0, 0);
    }
    {
      float xs = xp[t * BATCH + (gbB << 4) + l16];
      u64 hw = 0, lw = 0;
#pragma unroll
      for (int r = 0; r < 4; ++r) {
        float pre = hhB[r] + lhB[r] + hlB[r] + xs * win4[r];
        float mm = fmaxf(fabsf(pre) + bm4[r], 0.f);
        float hv = (pre > 0.f) ? mm : ((pre < 0.f) ? -mm : 0.f);
        u16 hbv = f2bf(hv);
        u16 lbv = f2bf(hv - bf2f(hbv));
        hw |= ((u64)hbv) << (16 * r);
        lw |= ((u64)lbv) << (16 * r);
      }
      int idx = (l16 << 9) + hbase;
      __hip_atomic_store((u64*)(nHB + idx), hw, __ATOMIC_RELAXED,
                         __HIP_MEMORY_SCOPE_AGENT);
      __hip_atomic_store((u64*)(nLB + idx), lw, __ATOMIC_RELAXED,
                         __HIP_MEMORY_SCOPE_AGENT);
    }
    asm volatile("s_waitcnt vmcnt(0)" ::: "memory");
    __syncthreads();
    if (tid == 0)
      __hip_atomic_store(myflagB, (unsigned)(t + 1), __ATOMIC_RELAXED,
                         __HIP_MEMORY_SCOPE_AGENT);

    // ---- fused spin over both chains' 16 flags [R6 protocol, widened] ----
    const unsigned target = (unsigned)(t + 1);
    int spin = 0;
    for (;;) {
      unsigned fl = __hip_atomic_load(poll + ((lane & 15) << 5), __ATOMIC_RELAXED,
                                      __HIP_MEMORY_SCOPE_AGENT);
      if (__ballot(fl >= target) == ~0ull) break;
      __builtin_amdgcn_s_sleep(1);
      if (++spin > (1 << 15)) break;  // diagnosability valve (R11-proven)
    }
    __builtin_amdgcn_sched_barrier(0);  // no hoisting of next stage above spin
  }

  // ---- head: final h in buffer 0 (t=783 odd -> g0); both chains ----
  if (cg == 0) {
#pragma unroll 1
    for (int sel = 0; sel < 2; ++sel) {
      const u64* fH = (const u64*)(sel ? g0hB : g0hA);
      const u64* fL = (const u64*)(sel ? g0lB : g0lA);
      const int gb = sel ? gbB : gbA;
      __syncthreads();  // tile reuse guard across sel iterations
      u64 qh[8], ql[8];
#pragma unroll
      for (int i = 0; i < 8; ++i) {
        qh[i] = __hip_atomic_load(fH + tid + (i << 8), __ATOMIC_RELAXED,
                                  __HIP_MEMORY_SCOPE_AGENT);
        ql[i] = __hip_atomic_load(fL + tid + (i << 8), __ATOMIC_RELAXED,
                                  __HIP_MEMORY_SCOPE_AGENT);
      }
#pragma unroll
      for (int i = 0; i < 8; ++i) {
        int f = tid + (i << 8);
        int r = f >> 7;
        unsigned du = (unsigned)(f & 127) << 1;
        unsigned phys = ((unsigned)r << 8) | (du ^ ((r & 7) << 2));
        *(u64*)(tHiA + phys) = qh[i];
        *(u64*)(tLoA + phys) = ql[i];
      }
      __syncthreads();
      int row = tid >> 4;
      int cls = tid & 15;
      if (cls < NCLS) {
        float acc = b_lin[cls];
        const float* wl = W_lin + cls * HDIM;
        for (int k = 0; k < HDIM; ++k) {
          unsigned phys = ((unsigned)row << 8) |
                          (((unsigned)k >> 1) ^ (((unsigned)row & 7) << 2));
          unsigned sh = ((unsigned)k & 1) << 4;
          float hv = bf2f((tHiA[phys] >> sh) & 0xFFFFu) +
                     bf2f((tLoA[phys] >> sh) & 0xFFFFu);
          acc = fmaf(hv, wl[k], acc);
        }
        out[((gb << 4) + row) * NCLS + cls] = acc;
      }
    }
  }
}

extern "C" void kernel_launch(void* const* d_in, const int* in_sizes, int n_in,
                              void* d_out, int out_size, void* d_ws, size_t ws_size,
                              hipStream_t stream) {
  const float* inputs = (const float*)d_in[0];  // 256x784
  const int* perm = (const int*)d_in[1];        // 784 (int64 -> int32 by harness)
  const float* W_skew = (const float*)d_in[2];  // 512x512
  const float* W_in = (const float*)d_in[3];    // 512
  const float* b_mod = (const float*)d_in[4];   // 512
  const float* W_lin = (const float*)d_in[5];   // 10x512
  const float* b_lin = (const float*)d_in[6];   // 10
  float* out = (float*)d_out;

  char* ws = (char*)d_ws;
  unsigned* flags = (unsigned*)ws;            // 32 KB (step flags)
  u16* h0hi = (u16*)(ws + 32768);             // 4 planes x 256 KB = 1 MB
  u16* h0lo = h0hi + BATCH * HDIM;
  u16* h1hi = h0lo + BATCH * HDIM;
  u16* h1lo = h1hi + BATCH * HDIM;
  float* xp = (float*)(h1lo + BATCH * HDIM);  // 0.77 MB
  float* X = xp + TSTEPS * BATCH;             // 1 MB
  float* P = X + HDIM * HDIM;                 // 1 MB
  float* Q = P + HDIM * HDIM;                 // 1 MB  (total ~4.9 MB)

  hipMemsetAsync(flags, 0, 32768, stream);
  hipMemsetAsync(h0hi, 0, (size_t)BATCH * HDIM * 2 * sizeof(u16), stream);  // h0 hi+lo

  gather_xp<<<TSTEPS, 256, 0, stream>>>(inputs, perm, xp);
  build_X<<<(HDIM * HDIM) / 256, 256, 0, stream>>>(W_skew, X);

  // expm(A) = (T6(A/32))^(2^5), Horner -- fp32 gemm512 [R2-R8 proven numerics]
  axpyI<<<(HDIM * HDIM) / 256, 256, 0, stream>>>(P, X, 1.f / 6.f);
  float* a = P;
  float* b = Q;
  for (int k = 5; k >= 1; --k) {
    gemm512<<<dim3(8, 8), dim3(16, 16), 0, stream>>>(b, X, a, 1.f / (float)k, 1);
    float* tmp = a; a = b; b = tmp;
  }
  for (int i = 0; i < 5; ++i) {
    gemm512<<<dim3(8, 8), dim3(16, 16), 0, stream>>>(b, a, a, 1.f, 0);
    float* tmp = a; a = b; b = tmp;
  }
  // a == P (10 swaps -> back to P)

  rnn_main<<<NPAIR * WGPG, 256, 0, stream>>>(xp, a, W_in, b_mod, W_lin, b_lin,
                                             h0hi, h0lo, h1hi, h1lo, flags, out);
  (void)in_sizes; (void)n_in; (void)out_size; (void)ws_size;
}

// Round 5
// 2993.690 us; speedup vs baseline: 921.7574x; 1.4873x over previous
//
#include <hip/hip_runtime.h>

#define TSTEPS 784
#define BATCH  256
#define HDIM   512
#define NCLS   10
#define NGRP   16
#define WGPG   8

typedef __bf16 bf16x8 __attribute__((ext_vector_type(8)));
typedef float  f32x4  __attribute__((ext_vector_type(4)));
typedef unsigned uint4v __attribute__((ext_vector_type(4)));
typedef unsigned long long u64;
typedef unsigned short u16;

static __device__ __forceinline__ u16 f2bf(float f) {
  unsigned u = __builtin_bit_cast(unsigned, f);
  u += 0x7fffu + ((u >> 16) & 1u);
  return (u16)(u >> 16);
}
static __device__ __forceinline__ float bf2f(unsigned s) {
  unsigned u = s << 16;
  return __builtin_bit_cast(float, u);
}

// ---------------- xp[t][b] = inputs[b][perm[t]] ----------------
__global__ __launch_bounds__(256) void gather_xp(const float* __restrict__ in,
                                                 const int* __restrict__ perm,
                                                 float* __restrict__ xp) {
  int t = blockIdx.x;
  int b = threadIdx.x;
  int p = perm[t];
  p = (p < 0) ? 0 : (p >= TSTEPS ? TSTEPS - 1 : p);
  xp[t * BATCH + b] = in[b * TSTEPS + p];
}

// ---------------- X = (triu(W,1) - triu(W,1)^T) / 32 ----------------
__global__ __launch_bounds__(256) void build_X(const float* __restrict__ W,
                                               float* __restrict__ X) {
  int idx = blockIdx.x * 256 + threadIdx.x;
  int i = idx >> 9, j = idx & 511;
  float v = 0.f;
  if (j > i) v = W[i * HDIM + j];
  else if (i > j) v = -W[j * HDIM + i];
  X[idx] = v * 0.03125f;
}

// ---------------- P = coef*X + I ----------------
__global__ __launch_bounds__(256) void axpyI(float* __restrict__ P,
                                             const float* __restrict__ X, float coef) {
  int idx = blockIdx.x * 256 + threadIdx.x;
  int i = idx >> 9, j = idx & 511;
  P[idx] = coef * X[idx] + ((i == j) ? 1.f : 0.f);
}

// ---------------- C = alpha*A*B (+I), 512^3 fp32, 64x64 tile ----------------
// fp32 vector GEMM [R2-R8 proven]. The expm chain NEEDS fp32-class accuracy:
// split-bf16 here gave delta(Borth) ~1e-2 after 5 squarings -> absmax 12 (R9).
__global__ __launch_bounds__(256) void gemm512(float* __restrict__ C,
                                               const float* __restrict__ A,
                                               const float* __restrict__ B,
                                               float alpha, int addI) {
  __shared__ float As[16][68];
  __shared__ float Bs[16][68];
  const int tx = threadIdx.x, ty = threadIdx.y;
  const int tid = ty * 16 + tx;
  const int ib = blockIdx.y, jb = blockIdx.x;
  const int ra = tid >> 2, ca = (tid & 3) << 2;
  const int rb = tid >> 4, cb = (tid & 15) << 2;
  float acc[4][4] = {};
  for (int kt = 0; kt < HDIM / 16; ++kt) {
    f32x4 av = *(const f32x4*)(A + (ib * 64 + ra) * HDIM + kt * 16 + ca);
    f32x4 bv = *(const f32x4*)(B + (kt * 16 + rb) * HDIM + jb * 64 + cb);
    __syncthreads();
    As[ca + 0][ra] = av[0];
    As[ca + 1][ra] = av[1];
    As[ca + 2][ra] = av[2];
    As[ca + 3][ra] = av[3];
    *(f32x4*)&Bs[rb][cb] = bv;
    __syncthreads();
#pragma unroll
    for (int kk = 0; kk < 16; ++kk) {
      f32x4 a4 = *(const f32x4*)&As[kk][ty << 2];
      f32x4 b4 = *(const f32x4*)&Bs[kk][tx << 2];
#pragma unroll
      for (int u = 0; u < 4; ++u)
#pragma unroll
        for (int v = 0; v < 4; ++v) acc[u][v] = fmaf(a4[u], b4[v], acc[u][v]);
    }
  }
#pragma unroll
  for (int u = 0; u < 4; ++u)
#pragma unroll
    for (int v = 0; v < 4; ++v) {
      int r = ib * 64 + (ty << 2) + u, c = jb * 64 + (tx << 2) + v;
      float val = alpha * acc[u][v];
      if (addI && r == c) val += 1.f;
      C[r * HDIM + c] = val;
    }
}

// ---------------- persistent RNN scan [R14: R13 + LDS addr fix] -------------
// R13 (tagged-data flagless sync) failed with absmax 1e38: the packed tile
// widened rows to 512 dwords but the fragment read kept R3's "+4" second
// granule -- (dc0^swz)+4 != (dc0+4)^swz when swz bit2=1, so every odd-l16
// thread read its upper 4 h-elements from the wrong slot. Wrong-but-finite
// h data = random non-orthogonal map per step -> exponential blowup over
// 784 steps -> 1e38. R14 fixes the second-granule address; protocol
// unchanged:
//   h packed u32 = (hi_bf16<<16)|lo_bf16, bit0 of lo = step tag
//   ((s>>1)&1). Consumers poll-load the DATA (sc1 = device scope; u32
//   single-copy atomic, per-dword self-validating), retry until all 32
//   tags fresh. Producer just ISSUES its packed dwordx4 store -- no drain,
//   no flag, no spin-wait on others' flags. One-step skew overwrite hazard
//   covered by per-granule revalidation (coherence order per location).
// Operand-swapped MFMA (R3-validated): D = pre^T, thread owns 4 consecutive
// h-cols at one batch row -> epilogue = ONE dwordx4 store.
__global__ __launch_bounds__(256, 1) void rnn_main(
    const float* __restrict__ xp, const float* __restrict__ Borth,
    const float* __restrict__ W_in, const float* __restrict__ b_mod,
    const float* __restrict__ W_lin, const float* __restrict__ b_lin,
    unsigned* __restrict__ h0, unsigned* __restrict__ h1,
    float* __restrict__ out) {
  __shared__ unsigned tile0[8192], tile1[8192];  // 32 KB x 2 (double buffer)

  const int wg = blockIdx.x;
  const int gb = wg & 15;
  const int cg = wg >> 4;
  const int tid = threadIdx.x;
  const int wave = tid >> 6;
  const int lane = tid & 63;
  const int quad = lane >> 4;
  const int l16 = lane & 15;
  const int colg = (cg << 6) + (wave << 4) + l16;           // Bf column
  const int hbase = (cg << 6) + (wave << 4) + (quad << 2);  // epilogue h-col base

  // Borth fragments (round-hi split, R3-proven numerics)
  bf16x8 Bfh[16], Bfl[16];
#pragma unroll
  for (int ki = 0; ki < 16; ++ki) {
#pragma unroll
    for (int j = 0; j < 8; ++j) {
      int k = (ki << 5) + (quad << 3) + j;
      float v = Borth[k * HDIM + colg];
      u16 hb = f2bf(v);
      u16 lb = f2bf(v - bf2f(hb));
      Bfh[ki][j] = __builtin_bit_cast(__bf16, hb);
      Bfl[ki][j] = __builtin_bit_cast(__bf16, lb);
    }
  }
  const f32x4 win4 = *(const f32x4*)(W_in + hbase);
  const f32x4 bm4 = *(const f32x4*)(b_mod + hbase);

  const u64 b0 = (u64)(h0 + (gb << 13));  // 8192 u32 = 32 KB per group
  const u64 b1 = (u64)(h1 + (gb << 13));
  // poll voffsets: granule g = tid + g*256 -> byte off *16
  const unsigned vo0 = (unsigned)((tid + 0 * 256) << 4);
  const unsigned vo1 = (unsigned)((tid + 1 * 256) << 4);
  const unsigned vo2 = (unsigned)((tid + 2 * 256) << 4);
  const unsigned vo3 = (unsigned)((tid + 3 * 256) << 4);
  const unsigned vo4 = (unsigned)((tid + 4 * 256) << 4);
  const unsigned vo5 = (unsigned)((tid + 5 * 256) << 4);
  const unsigned vo6 = (unsigned)((tid + 6 * 256) << 4);
  const unsigned vo7 = (unsigned)((tid + 7 * 256) << 4);
  const unsigned soff = (unsigned)(((l16 << 9) + hbase) << 2);  // store byte off
  const unsigned swz = (unsigned)((l16 & 7) << 2);

  for (int t = 0; t < TSTEPS; ++t) {
    const u64 rb = (t & 1) ? b1 : b0;
    const u64 wb = (t & 1) ? b0 : b1;
    const unsigned rtag = (unsigned)((t >> 1) & 1);
    const unsigned wtag = (unsigned)(((t + 1) >> 1) & 1);
    unsigned* const tl = (t & 1) ? tile1 : tile0;

    // ---- tagged poll-load: retry own 8 granules until all tags fresh ----
    uint4v q0, q1, q2, q3, q4, q5, q6, q7;
    int spin = 0;
    for (;;) {
      asm volatile(
          "global_load_dwordx4 %[q0], %[v0], %[b] sc1\n\t"
          "global_load_dwordx4 %[q1], %[v1], %[b] sc1\n\t"
          "global_load_dwordx4 %[q2], %[v2], %[b] sc1\n\t"
          "global_load_dwordx4 %[q3], %[v3], %[b] sc1\n\t"
          "global_load_dwordx4 %[q4], %[v4], %[b] sc1\n\t"
          "global_load_dwordx4 %[q5], %[v5], %[b] sc1\n\t"
          "global_load_dwordx4 %[q6], %[v6], %[b] sc1\n\t"
          "global_load_dwordx4 %[q7], %[v7], %[b] sc1\n\t"
          "s_waitcnt vmcnt(0)"
          : [q0] "=&v"(q0), [q1] "=&v"(q1), [q2] "=&v"(q2), [q3] "=&v"(q3),
            [q4] "=&v"(q4), [q5] "=&v"(q5), [q6] "=&v"(q6), [q7] "=&v"(q7)
          : [v0] "v"(vo0), [v1] "v"(vo1), [v2] "v"(vo2), [v3] "v"(vo3),
            [v4] "v"(vo4), [v5] "v"(vo5), [v6] "v"(vo6), [v7] "v"(vo7),
            [b] "s"(rb));
      unsigned bad = 0;
#define TCHK(q) bad |= (q[0] ^ rtag) | (q[1] ^ rtag) | (q[2] ^ rtag) | (q[3] ^ rtag)
      TCHK(q0); TCHK(q1); TCHK(q2); TCHK(q3);
      TCHK(q4); TCHK(q5); TCHK(q6); TCHK(q7);
#undef TCHK
      if (!(bad & 1u)) break;
      __builtin_amdgcn_s_sleep(1);
      if (++spin > (1 << 11)) break;  // diagnosability valve
    }
    __builtin_amdgcn_sched_barrier(0);

    // ---- LDS stage (swizzled: phys = row<<9 | (dcol ^ ((row&7)<<2))) ----
#define STG(g, q)                                                      \
  {                                                                    \
    int G = tid + ((g) << 8);                                          \
    int r = G >> 7;                                                    \
    unsigned dc = (unsigned)(G & 127) << 2;                            \
    unsigned phys = ((unsigned)r << 9) | (dc ^ ((unsigned)(r & 7) << 2)); \
    *(uint4v*)(tl + phys) = q;                                         \
  }
    STG(0, q0) STG(1, q1) STG(2, q2) STG(3, q3)
    STG(4, q4) STG(5, q5) STG(6, q6) STG(7, q7)
#undef STG
    __syncthreads();

    // ---- fragment reads + perm hi/lo split + swapped split-bf16 MFMA ----
    // R14 FIX: second granule lives at (dc0+4)^swz, NOT (dc0^swz)+4.
    f32x4 hh = {0.f, 0.f, 0.f, 0.f};
    f32x4 lh = {0.f, 0.f, 0.f, 0.f};
    f32x4 hl = {0.f, 0.f, 0.f, 0.f};
#pragma unroll
    for (int ki = 0; ki < 16; ++ki) {
      unsigned dc0 = (unsigned)((ki << 5) + (quad << 3));
      unsigned base = (unsigned)l16 << 9;
      unsigned offL = base + (dc0 ^ swz);
      unsigned offH = base + ((dc0 + 4) ^ swz);
      uint4v e0 = *(const uint4v*)(tl + offL);
      uint4v e1 = *(const uint4v*)(tl + offH);
      uint4v ahv, alv;
      ahv[0] = __builtin_amdgcn_perm(e0[1], e0[0], 0x07060302u);
      ahv[1] = __builtin_amdgcn_perm(e0[3], e0[2], 0x07060302u);
      ahv[2] = __builtin_amdgcn_perm(e1[1], e1[0], 0x07060302u);
      ahv[3] = __builtin_amdgcn_perm(e1[3], e1[2], 0x07060302u);
      alv[0] = __builtin_amdgcn_perm(e0[1], e0[0], 0x05040100u);
      alv[1] = __builtin_amdgcn_perm(e0[3], e0[2], 0x05040100u);
      alv[2] = __builtin_amdgcn_perm(e1[1], e1[0], 0x05040100u);
      alv[3] = __builtin_amdgcn_perm(e1[3], e1[2], 0x05040100u);
      bf16x8 ah = __builtin_bit_cast(bf16x8, ahv);
      bf16x8 al = __builtin_bit_cast(bf16x8, alv);
      hh = __builtin_amdgcn_mfma_f32_16x16x32_bf16(Bfh[ki], ah, hh, 0, 0, 0);
      lh = __builtin_amdgcn_mfma_f32_16x16x32_bf16(Bfh[ki], al, lh, 0, 0, 0);
      hl = __builtin_amdgcn_mfma_f32_16x16x32_bf16(Bfl[ki], ah, hl, 0, 0, 0);
    }

    // ---- epilogue: D = pre^T (thread: batchrow=l16, h-cols hbase..+3) ----
    {
      float xs = xp[t * BATCH + (gb << 4) + l16];
      uint4v sv;
#pragma unroll
      for (int r = 0; r < 4; ++r) {
        float pre = hh[r] + lh[r] + hl[r] + xs * win4[r];
        float mm = fmaxf(fabsf(pre) + bm4[r], 0.f);
        float hv = (pre > 0.f) ? mm : ((pre < 0.f) ? -mm : 0.f);
        u16 hbv = f2bf(hv);
        u16 lbv = f2bf(hv - bf2f(hbv));
        sv[r] = ((unsigned)hbv << 16) | (unsigned)((lbv & 0xFFFEu) | wtag);
      }
      asm volatile("global_store_dwordx4 %[o], %[d], %[b] sc1" ::[o] "v"(soff),
                   [d] "v"(sv), [b] "s"(wb));
    }
    // no drain, no flag: next poll's vmcnt(0) covers the anti-overwrite
    // hazard (store is >= 1 full step old before its buffer is re-read).
  }

  // ---- head: h_784 in buffer 0, tag (784>>1)&1 = 0; poll + LDS + dot ----
  if (cg == 0) {
    uint4v q0, q1, q2, q3, q4, q5, q6, q7;
    const unsigned rtag = 0u;
    int spin = 0;
    for (;;) {
      asm volatile(
          "global_load_dwordx4 %[q0], %[v0], %[b] sc1\n\t"
          "global_load_dwordx4 %[q1], %[v1], %[b] sc1\n\t"
          "global_load_dwordx4 %[q2], %[v2], %[b] sc1\n\t"
          "global_load_dwordx4 %[q3], %[v3], %[b] sc1\n\t"
          "global_load_dwordx4 %[q4], %[v4], %[b] sc1\n\t"
          "global_load_dwordx4 %[q5], %[v5], %[b] sc1\n\t"
          "global_load_dwordx4 %[q6], %[v6], %[b] sc1\n\t"
          "global_load_dwordx4 %[q7], %[v7], %[b] sc1\n\t"
          "s_waitcnt vmcnt(0)"
          : [q0] "=&v"(q0), [q1] "=&v"(q1), [q2] "=&v"(q2), [q3] "=&v"(q3),
            [q4] "=&v"(q4), [q5] "=&v"(q5), [q6] "=&v"(q6), [q7] "=&v"(q7)
          : [v0] "v"(vo0), [v1] "v"(vo1), [v2] "v"(vo2), [v3] "v"(vo3),
            [v4] "v"(vo4), [v5] "v"(vo5), [v6] "v"(vo6), [v7] "v"(vo7),
            [b] "s"(b0));
      unsigned bad = 0;
#define TCHK(q) bad |= (q[0] ^ rtag) | (q[1] ^ rtag) | (q[2] ^ rtag) | (q[3] ^ rtag)
      TCHK(q0); TCHK(q1); TCHK(q2); TCHK(q3);
      TCHK(q4); TCHK(q5); TCHK(q6); TCHK(q7);
#undef TCHK
      if (!(bad & 1u)) break;
      __builtin_amdgcn_s_sleep(1);
      if (++spin > (1 << 11)) break;
    }
    __builtin_amdgcn_sched_barrier(0);
#define STG(g, q)                                                      \
  {                                                                    \
    int G = tid + ((g) << 8);                                          \
    int r = G >> 7;                                                    \
    unsigned dc = (unsigned)(G & 127) << 2;                            \
    unsigned phys = ((unsigned)r << 9) | (dc ^ ((unsigned)(r & 7) << 2)); \
    *(uint4v*)(tile0 + phys) = q;                                      \
  }
    STG(0, q0) STG(1, q1) STG(2, q2) STG(3, q3)
    STG(4, q4) STG(5, q5) STG(6, q6) STG(7, q7)
#undef STG
    __syncthreads();
    int row = tid >> 4;
    int cls = tid & 15;
    if (cls < NCLS) {
      float acc = b_lin[cls];
      const float* wl = W_lin + cls * HDIM;
      for (int k = 0; k < HDIM; ++k) {
        unsigned phys = ((unsigned)row << 9) |
                        ((unsigned)k ^ (((unsigned)row & 7) << 2));
        unsigned x = tile0[phys];
        float hv = bf2f(x >> 16) + bf2f(x & 0xFFFFu);
        acc = fmaf(hv, wl[k], acc);
      }
      out[((gb << 4) + row) * NCLS + cls] = acc;
    }
  }
}

extern "C" void kernel_launch(void* const* d_in, const int* in_sizes, int n_in,
                              void* d_out, int out_size, void* d_ws, size_t ws_size,
                              hipStream_t stream) {
  const float* inputs = (const float*)d_in[0];  // 256x784
  const int* perm = (const int*)d_in[1];        // 784 (int64 -> int32 by harness)
  const float* W_skew = (const float*)d_in[2];  // 512x512
  const float* W_in = (const float*)d_in[3];    // 512
  const float* b_mod = (const float*)d_in[4];   // 512
  const float* W_lin = (const float*)d_in[5];   // 10x512
  const float* b_lin = (const float*)d_in[6];   // 10
  float* out = (float*)d_out;

  char* ws = (char*)d_ws;
  unsigned* h0 = (unsigned*)ws;               // 512 KB (packed hi|lo u32)
  unsigned* h1 = h0 + BATCH * HDIM;           // 512 KB
  float* xp = (float*)(h1 + BATCH * HDIM);    // 0.77 MB
  float* X = xp + TSTEPS * BATCH;             // 1 MB
  float* P = X + HDIM * HDIM;                 // 1 MB
  float* Q = P + HDIM * HDIM;                 // 1 MB (total ~4.8 MB)

  // h0 = zeros, tag bit 0 -> valid for t=0 (h0 IS zero).
  // h1 = 0x01010101 -> tag bit 1 = INVALID for first read (t=1 expects 0).
  hipMemsetAsync(h0, 0, (size_t)BATCH * HDIM * 4, stream);
  hipMemsetAsync(h1, 0x01, (size_t)BATCH * HDIM * 4, stream);

  gather_xp<<<TSTEPS, 256, 0, stream>>>(inputs, perm, xp);
  build_X<<<(HDIM * HDIM) / 256, 256, 0, stream>>>(W_skew, X);

  // expm(A) = (T6(A/32))^(2^5), Horner -- fp32 gemm512 [R2-R8 proven numerics]
  axpyI<<<(HDIM * HDIM) / 256, 256, 0, stream>>>(P, X, 1.f / 6.f);
  float* a = P;
  float* b = Q;
  for (int k = 5; k >= 1; --k) {
    gemm512<<<dim3(8, 8), dim3(16, 16), 0, stream>>>(b, X, a, 1.f / (float)k, 1);
    float* tmp = a; a = b; b = tmp;
  }
  for (int i = 0; i < 5; ++i) {
    gemm512<<<dim3(8, 8), dim3(16, 16), 0, stream>>>(b, a, a, 1.f, 0);
    float* tmp = a; a = b; b = tmp;
  }
  // a == P (10 swaps -> back to P)

  rnn_main<<<NGRP * WGPG, 256, 0, stream>>>(xp, a, W_in, b_mod, W_lin, b_lin,
                                            h0, h1, out);
  (void)in_sizes; (void)n_in; (void)out_size; (void)ws_size;
}